// Round 1
// baseline (279.886 us; speedup 1.0000x reference)
//
#include <hip/hip_runtime.h>

#define BB 262144
#define TT 20
#define HH 10

__device__ __forceinline__ float frcp(float x) { return __builtin_amdgcn_rcpf(x); }
__device__ __forceinline__ float fsig(float x) { return frcp(1.0f + __expf(-x)); }
__device__ __forceinline__ float ftanh(float x) { return 1.0f - 2.0f * frcp(__expf(2.0f * x) + 1.0f); }

__global__ __launch_bounds__(256) void lstm_disc_kernel(
    const float* __restrict__ values, const float* __restrict__ masks,
    const float* __restrict__ W_ih, const float* __restrict__ W_hh,
    const float* __restrict__ b_ih, const float* __restrict__ b_hh,
    const float* __restrict__ W1, const float* __restrict__ b1,
    const float* __restrict__ W2, const float* __restrict__ b2,
    const int* __restrict__ directp,
    float* __restrict__ out)
{
    const int b = blockIdx.x * blockDim.x + threadIdx.x;
    if (b >= BB) return;
    const int dir = *directp;

    // ---- load this sequence's values row (80B, 16B-aligned) ----
    float vals[TT];
    const float4* vrow = reinterpret_cast<const float4*>(values + (size_t)b * TT);
    #pragma unroll
    for (int i = 0; i < TT / 4; ++i) {
        float4 v = vrow[i];
        vals[4 * i + 0] = v.x; vals[4 * i + 1] = v.y;
        vals[4 * i + 2] = v.z; vals[4 * i + 3] = v.w;
    }
    if (dir != 0) {  // uniform branch; register-only swap with constant indices
        #pragma unroll
        for (int i = 0; i < TT / 2; ++i) {
            float tmp = vals[i]; vals[i] = vals[TT - 1 - i]; vals[TT - 1 - i] = tmp;
        }
    }

    float h[HH], c[HH], sc[TT];
    #pragma unroll
    for (int j = 0; j < HH; ++j) { h[j] = 0.0f; c[j] = 0.0f; }

    #pragma unroll
    for (int t = 0; t < TT; ++t) {
        // ---- score head on PRE-update h ----
        float z = b2[0];
        #pragma unroll
        for (int m = 0; m < 5; ++m) {
            float a = b1[m];
            #pragma unroll
            for (int j = 0; j < HH; ++j) a += h[j] * W1[m * HH + j];
            a = (a > 0.0f) ? a : 0.2f * a;   // leaky_relu(0.2)
            z += a * W2[m];
        }
        sc[t] = fsig(z);

        // ---- gates: x*w_x + h @ W_hh.T + (b_ih + b_hh) ----
        const float x = vals[t];
        float hn[HH];
        #pragma unroll
        for (int j = 0; j < HH; ++j) {
            float gi = x * W_ih[j]          + (b_ih[j]          + b_hh[j]);
            float gf = x * W_ih[HH + j]     + (b_ih[HH + j]     + b_hh[HH + j]);
            float gg = x * W_ih[2 * HH + j] + (b_ih[2 * HH + j] + b_hh[2 * HH + j]);
            float go = x * W_ih[3 * HH + j] + (b_ih[3 * HH + j] + b_hh[3 * HH + j]);
            #pragma unroll
            for (int k = 0; k < HH; ++k) {
                gi += h[k] * W_hh[(j) * HH + k];
                gf += h[k] * W_hh[(HH + j) * HH + k];
                gg += h[k] * W_hh[(2 * HH + j) * HH + k];
                go += h[k] * W_hh[(3 * HH + j) * HH + k];
            }
            float cn = fsig(gf) * c[j] + fsig(gi) * ftanh(gg);
            c[j] = cn;
            hn[j] = fsig(go) * ftanh(cn);
        }
        #pragma unroll
        for (int j = 0; j < HH; ++j) h[j] = hn[j];
    }

    // ---- write scores row ----
    float4* s4 = reinterpret_cast<float4*>(out + (size_t)b * TT);
    #pragma unroll
    for (int i = 0; i < TT / 4; ++i) {
        float4 v;
        v.x = sc[4 * i + 0]; v.y = sc[4 * i + 1];
        v.z = sc[4 * i + 2]; v.w = sc[4 * i + 3];
        s4[i] = v;
    }

    // ---- masks pass-through (second output), fused to avoid extra launch ----
    const float* mrow = masks + (size_t)b * TT;
    float* mout = out + (size_t)BB * TT + (size_t)b * TT;
    if (dir == 0) {
        const float4* m4 = reinterpret_cast<const float4*>(mrow);
        float4* o4 = reinterpret_cast<float4*>(mout);
        #pragma unroll
        for (int i = 0; i < TT / 4; ++i) o4[i] = m4[i];
    } else {
        #pragma unroll
        for (int t = 0; t < TT; ++t) mout[t] = mrow[TT - 1 - t];
    }
}

extern "C" void kernel_launch(void* const* d_in, const int* in_sizes, int n_in,
                              void* d_out, int out_size, void* d_ws, size_t ws_size,
                              hipStream_t stream) {
    const float* values = (const float*)d_in[0];
    const float* masks  = (const float*)d_in[1];
    const float* W_ih   = (const float*)d_in[2];
    const float* W_hh   = (const float*)d_in[3];
    const float* b_ih   = (const float*)d_in[4];
    const float* b_hh   = (const float*)d_in[5];
    const float* W1     = (const float*)d_in[6];
    const float* b1     = (const float*)d_in[7];
    const float* W2     = (const float*)d_in[8];
    const float* b2     = (const float*)d_in[9];
    const int*   direct = (const int*)d_in[11];
    float* out = (float*)d_out;

    const int block = 256;
    const int grid = (BB + block - 1) / block;
    lstm_disc_kernel<<<grid, block, 0, stream>>>(values, masks, W_ih, W_hh, b_ih, b_hh,
                                                 W1, b1, W2, b2, direct, out);
}

// Round 2
// 197.798 us; speedup vs baseline: 1.4150x; 1.4150x over previous
//
#include <hip/hip_runtime.h>

#define BB 262144
#define TT 20
#define HH 10

typedef float v2f __attribute__((ext_vector_type(2)));

__device__ __forceinline__ float frcp(float x) { return __builtin_amdgcn_rcpf(x); }
__device__ __forceinline__ float fexp(float x) { return __expf(x); }
__device__ __forceinline__ v2f vfma(v2f a, v2f b, v2f c) { return __builtin_elementwise_fma(a, b, c); }

__global__ __launch_bounds__(256, 2) void lstm_disc_kernel(
    const float* __restrict__ values, const float* __restrict__ masks,
    const float* __restrict__ W_ih, const float* __restrict__ W_hh,
    const float* __restrict__ b_ih, const float* __restrict__ b_hh,
    const float* __restrict__ W1, const float* __restrict__ b1,
    const float* __restrict__ W2, const float* __restrict__ b2,
    const int* __restrict__ directp,
    float* __restrict__ out)
{
    const int b = blockIdx.x * blockDim.x + threadIdx.x;
    if (b >= BB) return;
    const int dir = *directp;

    const v2f* __restrict__ Wx2 = reinterpret_cast<const v2f*>(W_ih);   // 20 pairs
    const v2f* __restrict__ Wh2 = reinterpret_cast<const v2f*>(W_hh);   // 200 pairs
    const v2f* __restrict__ W1v = reinterpret_cast<const v2f*>(W1);     // 25 pairs
    const v2f* __restrict__ bi2 = reinterpret_cast<const v2f*>(b_ih);
    const v2f* __restrict__ bh2 = reinterpret_cast<const v2f*>(b_hh);

    // hoisted loop invariants: combined biases (40 floats = 20 pairs)
    v2f bb[20];
    #pragma unroll
    for (int i = 0; i < 20; ++i) bb[i] = bi2[i] + bh2[i];

    // ---- load this sequence's values row (80B, 16B-aligned) ----
    float vals[TT];
    const float4* vrow = reinterpret_cast<const float4*>(values + (size_t)b * TT);
    #pragma unroll
    for (int i = 0; i < TT / 4; ++i) {
        float4 v = vrow[i];
        vals[4 * i + 0] = v.x; vals[4 * i + 1] = v.y;
        vals[4 * i + 2] = v.z; vals[4 * i + 3] = v.w;
    }
    if (dir != 0) {
        #pragma unroll
        for (int i = 0; i < TT / 2; ++i) {
            float tmp = vals[i]; vals[i] = vals[TT - 1 - i]; vals[TT - 1 - i] = tmp;
        }
    }

    v2f h2[HH / 2], c2[HH / 2];
    #pragma unroll
    for (int j = 0; j < HH / 2; ++j) { h2[j] = (v2f){0.f, 0.f}; c2[j] = (v2f){0.f, 0.f}; }

    float4* s4 = reinterpret_cast<float4*>(out + (size_t)b * TT);
    float sc0 = 0.f, sc1 = 0.f, sc2 = 0.f;

    #pragma unroll
    for (int t = 0; t < TT; ++t) {
        // ---- score head on PRE-update h (packed dot products) ----
        float z = b2[0];
        #pragma unroll
        for (int m = 0; m < 5; ++m) {
            v2f a2 = (v2f){0.f, 0.f};
            #pragma unroll
            for (int kk = 0; kk < 5; ++kk) a2 = vfma(h2[kk], W1v[m * 5 + kk], a2);
            float a = a2.x + a2.y + b1[m];
            a = (a > 0.0f) ? a : 0.2f * a;
            z = fmaf(a, W2[m], z);
        }
        float s = frcp(1.0f + fexp(-z));

        // ---- per-step gate biases: bx[n] = x*w_x[n] + (b_ih+b_hh)[n], packed ----
        const float x = vals[t];
        const v2f x2 = (v2f){x, x};
        v2f bx[20];
        #pragma unroll
        for (int i = 0; i < 20; ++i) bx[i] = vfma(x2, Wx2[i], bb[i]);

        // ---- gates + activations ----
        v2f hn2[HH / 2];
        #pragma unroll
        for (int j = 0; j < HH; ++j) {
            v2f ai = (v2f){0.f, 0.f}, af = (v2f){0.f, 0.f}, ag = (v2f){0.f, 0.f}, ao = (v2f){0.f, 0.f};
            #pragma unroll
            for (int kk = 0; kk < 5; ++kk) {
                ai = vfma(h2[kk], Wh2[(0 * HH + j) * 5 + kk], ai);
                af = vfma(h2[kk], Wh2[(1 * HH + j) * 5 + kk], af);
                ag = vfma(h2[kk], Wh2[(2 * HH + j) * 5 + kk], ag);
                ao = vfma(h2[kk], Wh2[(3 * HH + j) * 5 + kk], ao);
            }
            const int n0 = j, n1 = HH + j, n2 = 2 * HH + j, n3 = 3 * HH + j;
            float gi = ai.x + ai.y + bx[n0 >> 1][n0 & 1];
            float gf = af.x + af.y + bx[n1 >> 1][n1 & 1];
            float gg = ag.x + ag.y + bx[n2 >> 1][n2 & 1];
            float go = ao.x + ao.y + bx[n3 >> 1][n3 & 1];

            // sig(f)*c + sig(i)*tanh(g); fused rcp forms
            float ef = fexp(-gf);
            float sf = frcp(1.0f + ef);
            float ei = fexp(-gi);
            float eg = fexp(2.0f * gg);
            float prod = (eg - 1.0f) * frcp((1.0f + ei) * (eg + 1.0f));
            float cn = sf * c2[j >> 1][j & 1] + prod;
            c2[j >> 1][j & 1] = cn;
            float eo = fexp(-go);
            float ec = fexp(2.0f * cn);
            hn2[j >> 1][j & 1] = (ec - 1.0f) * frcp((1.0f + eo) * (ec + 1.0f));
        }
        #pragma unroll
        for (int j = 0; j < HH / 2; ++j) h2[j] = hn2[j];

        // ---- score writeback, float4 every 4 steps ----
        switch (t & 3) {
            case 0: sc0 = s; break;
            case 1: sc1 = s; break;
            case 2: sc2 = s; break;
            case 3: {
                float4 v; v.x = sc0; v.y = sc1; v.z = sc2; v.w = s;
                s4[t >> 2] = v;
                break;
            }
        }
    }

    // ---- masks pass-through (second output) ----
    const float* mrow = masks + (size_t)b * TT;
    float* mout = out + (size_t)BB * TT + (size_t)b * TT;
    if (dir == 0) {
        const float4* m4 = reinterpret_cast<const float4*>(mrow);
        float4* o4 = reinterpret_cast<float4*>(mout);
        #pragma unroll
        for (int i = 0; i < TT / 4; ++i) o4[i] = m4[i];
    } else {
        #pragma unroll
        for (int t = 0; t < TT; ++t) mout[t] = mrow[TT - 1 - t];
    }
}

extern "C" void kernel_launch(void* const* d_in, const int* in_sizes, int n_in,
                              void* d_out, int out_size, void* d_ws, size_t ws_size,
                              hipStream_t stream) {
    const float* values = (const float*)d_in[0];
    const float* masks  = (const float*)d_in[1];
    const float* W_ih   = (const float*)d_in[2];
    const float* W_hh   = (const float*)d_in[3];
    const float* b_ih   = (const float*)d_in[4];
    const float* b_hh   = (const float*)d_in[5];
    const float* W1     = (const float*)d_in[6];
    const float* b1     = (const float*)d_in[7];
    const float* W2     = (const float*)d_in[8];
    const float* b2     = (const float*)d_in[9];
    const int*   direct = (const int*)d_in[11];
    float* out = (float*)d_out;

    const int block = 256;
    const int grid = (BB + block - 1) / block;
    lstm_disc_kernel<<<grid, block, 0, stream>>>(values, masks, W_ih, W_hh, b_ih, b_hh,
                                                 W1, b1, W2, b2, direct, out);
}